// Round 19
// baseline (636.984 us; speedup 1.0000x reference)
//
#include <hip/hip_runtime.h>
#include <math.h>

typedef __attribute__((ext_vector_type(8))) __bf16 bf16x8;
typedef __attribute__((ext_vector_type(4))) float f32x4;
typedef __attribute__((ext_vector_type(4))) int i32x4;

#define NB 8
#define NC 2048
#define NHW 784
#define NROWS 6272   /* NB*NHW */
#define NM 8192
#define NNEI 9
#define NCAND 24
#define WTOP 14      /* per-wave (1024-key stripe) list length; P(stripe>14 of top-24)~1e-8 */
#define NKT 32       /* K-tiles of 64 (i8) */

static_assert(NROWS == NB * NHW, "dims");

__device__ __forceinline__ unsigned umin32(unsigned a, unsigned b) { return a < b ? a : b; }

// scale 20: 127/20=6.35 > max|z|~5.9 over 29.6M N(0,1) draws -> no clamping.
__device__ __forceinline__ signed char quant20(float v) {
  int q = (int)rintf(v * 20.f);
  q = q < -127 ? -127 : (q > 127 ? 127 : q);
  return (signed char)q;
}

// ---------- merged prep: feat->Af32/Ai8 (bid<12800) | mb->Bi8+Bhi+m2 ----------
__global__ __launch_bounds__(256) void prep_kernel(const float* __restrict__ feat,
                                                   const float* __restrict__ mb,
                                                   float* __restrict__ Af32,
                                                   signed char* __restrict__ Ai8,
                                                   signed char* __restrict__ Bi8,
                                                   __bf16* __restrict__ Bhi,
                                                   float* __restrict__ m2) {
  int bid = blockIdx.x;
  int tid = threadIdx.x;
  if (bid < 12800) {
    __shared__ float tile[32][33];
    int b = bid / 1600;
    int c0 = ((bid / 25) & 63) * 32;
    int hw0 = (bid % 25) * 32;
    int tx = tid & 31, ty = tid >> 5;
#pragma unroll
    for (int i = 0; i < 4; ++i) {
      int c = c0 + ty + i * 8;
      int hw = hw0 + tx;
      float v = 0.f;
      if (hw < NHW) v = feat[((size_t)b * NC + c) * NHW + hw];
      tile[ty + i * 8][tx] = v;
    }
    __syncthreads();
#pragma unroll
    for (int i = 0; i < 4; ++i) {
      int hwl = ty + i * 8;
      int hw = hw0 + hwl;
      if (hw < NHW) {
        int n = b * NHW + hw;
        float v = tile[tx][hwl];
        Af32[(size_t)n * NC + c0 + tx] = v;
        Ai8[(size_t)n * NC + c0 + tx] = quant20(v);
      }
    }
  } else {
    __shared__ float red[4];
    int m = bid - 12800;
    float ss = 0.f;
#pragma unroll
    for (int i = 0; i < NC / 256; ++i) {
      int c = tid + i * 256;
      float v = mb[(size_t)m * NC + c];
      Bi8[(size_t)m * NC + c] = quant20(v);
      Bhi[(size_t)m * NC + c] = (__bf16)v;
      ss += v * v;
    }
#pragma unroll
    for (int off = 32; off; off >>= 1) ss += __shfl_xor(ss, off);
    if ((tid & 63) == 0) red[tid >> 6] = ss;
    __syncthreads();
    if (tid == 0) m2[m] = red[0] + red[1] + red[2] + red[3];
  }
}

#define STAGE(SRC, DST) \
  __builtin_amdgcn_global_load_lds((const __attribute__((address_space(1))) void*)(SRC), \
                                   (__attribute__((address_space(3))) void*)(DST), 16, 0, 0)

// ---------- i8 mixed-shape GEMM (tail-packed) — R11 schedule, K=64/tile ----------
// score*16 = 16*m2 - dot_i32*0.08 (scale-20 quant; monotone, u16-clamped).
__global__ __launch_bounds__(512, 2) void gemm8_kernel(const signed char* __restrict__ Ai8,
                                                       const signed char* __restrict__ Bi8,
                                                       const float* __restrict__ m2,
                                                       unsigned short* __restrict__ dotq) {
  __shared__ __align__(16) char lds[131072];
  int tid = threadIdx.x;
  int lane = tid & 63, w = tid >> 6;
  int bid = blockIdx.x;
  int r = lane & 15, kq = lane >> 4;
  int r4 = (lane >> 4) * 4, cL = lane & 15;  // C/D: col=lane&15, row=(lane>>4)*4+reg (m89)

  if (bid >= 768) {
    // ---------- light path: rows 6144..6271, 32 cols/block, prefetched ----------
    int lb = bid - 768;
    size_t m0l = (size_t)(lb & 7) * 1024 + (size_t)(lb >> 3) * 32;  // XCD-stripe aligned
    int n0l = 6144 + w * 16;
    const signed char* aB = Ai8 + (size_t)(n0l + r) * NC + kq * 16;
    const signed char* bB0 = Bi8 + (m0l + r) * NC + kq * 16;
    const signed char* bB1 = Bi8 + (m0l + 16 + r) * NC + kq * 16;
    i32x4 acc0 = {}, acc1 = {};
    i32x4 a0 = *(const i32x4*)aB;
    i32x4 b0 = *(const i32x4*)bB0;
    i32x4 b1 = *(const i32x4*)bB1;
#pragma unroll 4
    for (int kt = 0; kt < NKT; ++kt) {
      int ktn = (kt + 1) & 31;                 // wrap prefetch at tail: harmless
      i32x4 an = *(const i32x4*)(aB + ktn * 64);
      i32x4 b0n = *(const i32x4*)(bB0 + ktn * 64);
      i32x4 b1n = *(const i32x4*)(bB1 + ktn * 64);
      acc0 = __builtin_amdgcn_mfma_i32_16x16x64_i8(a0, b0, acc0, 0, 0, 0);
      acc1 = __builtin_amdgcn_mfma_i32_16x16x64_i8(a0, b1, acc1, 0, 0, 0);
      a0 = an; b0 = b0n; b1 = b1n;
    }
#pragma unroll
    for (int g = 0; g < 2; ++g) {
      float m2g16 = m2[m0l + g * 16 + cL] * 16.f;
      i32x4 ac = g ? acc1 : acc0;
#pragma unroll
      for (int q = 0; q < 4; ++q) {
        int grow = n0l + r4 + q;
        int qi = (int)(m2g16 - (float)ac[q] * 0.08f);
        qi = qi < 0 ? 0 : (qi > 65535 ? 65535 : qi);
        dotq[(size_t)grow * NM + (m0l + g * 16 + cL)] = (unsigned short)qi;
      }
    }
    return;
  }

  // ---------- heavy path: 256x256 tile (rows 0..6143) ----------
  int xcd = bid & 7, lin = bid >> 3;
  int mt = xcd * 4 + (lin & 3), rtl = lin >> 2;        // rtl in [0,24)
  size_t n0 = (size_t)rtl * 256, m0 = (size_t)mt * 256;
  int wr = w >> 2, wc = w & 3;

  int p = lane & 3;
  const char* aSrc[2];
  const char* bSrc[2];
  int aDst[2], bDst[2];
#pragma unroll
  for (int j = 0; j < 2; ++j) {
    int rloc = (w * 2 + j) * 16 + (lane >> 2);
    int kqs = (p - (rloc >> 1)) & 3;            // inverse of read swizzle
    aSrc[j] = (const char*)Ai8 + (n0 + rloc) * NC + kqs * 16;
    bSrc[j] = (const char*)Bi8 + (m0 + rloc) * NC + kqs * 16;
    aDst[j] = (w * 2 + j) * 1024;
    bDst[j] = 16384 + (w * 2 + j) * 1024;
  }
  int s16 = (kq + (r >> 1)) & 3;                // 2-way bank aliasing only (free)
  int aRd = wr * 8192 + r * 64 + s16 * 16;
  int bRd = 16384 + wc * 4096 + r * 64 + s16 * 16;

  i32x4 acc[8][4] = {};

#pragma unroll
  for (int t = 0; t < 2; ++t) {
    int sb = t * 32768, kb = t * 64;
#pragma unroll
    for (int j = 0; j < 2; ++j)
      STAGE(aSrc[j] + kb, lds + sb + aDst[j]);
#pragma unroll
    for (int j = 0; j < 2; ++j)
      STAGE(bSrc[j] + kb, lds + sb + bDst[j]);
  }
  asm volatile("s_waitcnt vmcnt(4)" ::: "memory");   // K0 landed
  __builtin_amdgcn_s_barrier();
  __builtin_amdgcn_sched_barrier(0);

#pragma unroll 4
  for (int kt = 0; kt < NKT; ++kt) {
    int sb = (kt & 3) * 32768;
    int kt2 = (kt + 2) & 31;                    // wraps at tail: harmless re-stage
    int sb2 = (kt2 & 3) * 32768;
    int kb2 = kt2 * 64;
    i32x4 av[4], bv[4];
    // ---- P1: stage A(T+2) | read A0-3 + B0-3 | 16 MFMA ----
#pragma unroll
    for (int j = 0; j < 2; ++j)
      STAGE(aSrc[j] + kb2, lds + sb2 + aDst[j]);
#pragma unroll
    for (int f = 0; f < 4; ++f) av[f] = *(const i32x4*)(lds + sb + aRd + f * 1024);
#pragma unroll
    for (int g = 0; g < 4; ++g) bv[g] = *(const i32x4*)(lds + sb + bRd + g * 1024);
    __builtin_amdgcn_s_setprio(1);
#pragma unroll
    for (int f = 0; f < 4; ++f)
#pragma unroll
      for (int g = 0; g < 4; ++g)
        acc[f][g] = __builtin_amdgcn_mfma_i32_16x16x64_i8(av[f], bv[g], acc[f][g], 0, 0, 0);
    __builtin_amdgcn_s_setprio(0);
    // ---- P2: stage B(T+2) | read A4-7 | 16 MFMA ----
#pragma unroll
    for (int j = 0; j < 2; ++j)
      STAGE(bSrc[j] + kb2, lds + sb2 + bDst[j]);
#pragma unroll
    for (int f = 0; f < 4; ++f) av[f] = *(const i32x4*)(lds + sb + aRd + (f + 4) * 1024);
    __builtin_amdgcn_s_setprio(1);
#pragma unroll
    for (int f = 0; f < 4; ++f)
#pragma unroll
      for (int g = 0; g < 4; ++g)
        acc[f + 4][g] = __builtin_amdgcn_mfma_i32_16x16x64_i8(av[f], bv[g], acc[f + 4][g], 0, 0, 0);
    __builtin_amdgcn_s_setprio(0);
    // ---- boundary: counted wait (never 0): T+1 certified landed ----
    asm volatile("s_waitcnt vmcnt(4)" ::: "memory");
    __builtin_amdgcn_s_barrier();
    __builtin_amdgcn_sched_barrier(0);
  }

  float m2r16[4];
#pragma unroll
  for (int g = 0; g < 4; ++g) m2r16[g] = m2[m0 + wc * 64 + g * 16 + cL] * 16.f;
#pragma unroll
  for (int f = 0; f < 8; ++f) {
    int grow0 = (int)n0 + wr * 128 + f * 16 + r4;
#pragma unroll
    for (int g = 0; g < 4; ++g) {
      size_t gcol = m0 + wc * 64 + g * 16 + cL;
#pragma unroll
      for (int q = 0; q < 4; ++q) {
        int qi = (int)(m2r16[g] - (float)acc[f][g][q] * 0.08f);
        qi = qi < 0 ? 0 : (qi > 65535 ? 65535 : qi);
        dotq[(size_t)(grow0 + q) * NM + gcol] = (unsigned short)qi;
      }
    }
  }
}

// ---------- selres: 8-wave stripe knockout (top-14/wave, 14 rounds) + merge + rescore ----------
// Wave w owns keys [w*1024,(w+1)*1024), 16/thread. Merged 8x14 sorted lists -> global
// top-24 by key (exact unless one stripe holds >=15 of top-24: P~1e-8/row).
__global__ __launch_bounds__(512, 2) void selres_kernel(const unsigned short* __restrict__ dotq,
                                                        const float* __restrict__ Af32,
                                                        const float* __restrict__ mb,
                                                        int* __restrict__ tki,
                                                        float* __restrict__ dsv) {
  __shared__ __align__(16) float fbuf[NC];
  __shared__ unsigned wl[8][WTOP];
  __shared__ int cidxL[NCAND];
  __shared__ double d2s[NCAND];
  int n = blockIdx.x;
  int tid = threadIdx.x;
  int lane = tid & 63, w = tid >> 6;

  // 16 packed keys (q<<13 | m) in registers; all accesses static after unroll
  unsigned kk[16];
  {
    const uint4* dq = (const uint4*)(dotq + (size_t)n * NM + tid * 16);
    unsigned base = tid * 16;
#pragma unroll
    for (int s = 0; s < 2; ++s) {
      uint4 v = dq[s];
      unsigned c0 = v.x, c1 = v.y, c2 = v.z, c3 = v.w;
      kk[s * 8 + 0] = ((c0 & 0xFFFFu) << 13) | (base + s * 8 + 0);
      kk[s * 8 + 1] = ((c0 >> 16) << 13)     | (base + s * 8 + 1);
      kk[s * 8 + 2] = ((c1 & 0xFFFFu) << 13) | (base + s * 8 + 2);
      kk[s * 8 + 3] = ((c1 >> 16) << 13)     | (base + s * 8 + 3);
      kk[s * 8 + 4] = ((c2 & 0xFFFFu) << 13) | (base + s * 8 + 4);
      kk[s * 8 + 5] = ((c2 >> 16) << 13)     | (base + s * 8 + 5);
      kk[s * 8 + 6] = ((c3 & 0xFFFFu) << 13) | (base + s * 8 + 6);
      kk[s * 8 + 7] = ((c3 >> 16) << 13)     | (base + s * 8 + 7);
    }
  }
#pragma unroll
  for (int i = 0; i < NC / 512; ++i)
    fbuf[tid + i * 512] = Af32[(size_t)n * NC + tid + i * 512];

  // per-wave knockout: WTOP rounds, shuffle-only (keys unique -> single owner lane)
  unsigned lmin = 0xFFFFFFFFu;
#pragma unroll
  for (int i = 0; i < 16; ++i) lmin = umin32(lmin, kk[i]);
  for (int r = 0; r < WTOP; ++r) {
    unsigned g = lmin;
#pragma unroll
    for (int off = 32; off; off >>= 1) g = umin32(g, (unsigned)__shfl_xor((int)g, off));
    if (lane == 0) wl[w][r] = g;
    if (lmin == g) {                       // owner lane only
#pragma unroll
      for (int i = 0; i < 16; ++i)
        if (kk[i] == g) kk[i] = 0xFFFFFFFFu;
      lmin = 0xFFFFFFFFu;
#pragma unroll
      for (int i = 0; i < 16; ++i) lmin = umin32(lmin, kk[i]);
    }
  }
  __syncthreads();

  // exact 8-way merge of sorted per-wave lists -> global top-24 (ascending)
  if (tid == 0) {
    int pp[8] = {0, 0, 0, 0, 0, 0, 0, 0};
    for (int r = 0; r < NCAND; ++r) {
      unsigned bk = 0xFFFFFFFFu;
      int bw = 0;
#pragma unroll
      for (int q = 0; q < 8; ++q) {
        unsigned hv = (pp[q] < WTOP) ? wl[q][pp[q]] : 0xFFFFFFFFu;
        if (hv < bk) { bk = hv; bw = q; }
      }
      pp[bw]++;
      cidxL[r] = (int)(bk & 8191u);
    }
  }
  __syncthreads();

  // wave-parallel fp64 rescore: wave w -> candidates {w, w+8, w+16},
  // float4 gathers + 4-way split fp64 accumulators
#pragma unroll
  for (int jj = 0; jj < NCAND / 8; ++jj) {
    int j = jj * 8 + w;
    const float* mrow = mb + (size_t)cidxL[j] * NC;
    float4 mv[8];
#pragma unroll
    for (int i = 0; i < 8; ++i) mv[i] = *(const float4*)(mrow + lane * 4 + i * 256);
    double a0 = 0.0, a1 = 0.0, a2 = 0.0, a3 = 0.0;
#pragma unroll
    for (int i = 0; i < 8; ++i) {
      float4 fv = *(const float4*)(&fbuf[lane * 4 + i * 256]);
      double d0 = (double)fv.x - (double)mv[i].x;
      double d1 = (double)fv.y - (double)mv[i].y;
      double d2 = (double)fv.z - (double)mv[i].z;
      double d3 = (double)fv.w - (double)mv[i].w;
      a0 += d0 * d0; a1 += d1 * d1; a2 += d2 * d2; a3 += d3 * d3;
    }
    double acc = (a0 + a1) + (a2 + a3);
#pragma unroll
    for (int off = 32; off; off >>= 1) acc += __shfl_xor(acc, off);
    if (lane == 0) d2s[j] = acc;
  }
  __syncthreads();

  if (tid == 0) {
    double dacc = 0.0;
    bool used[NCAND] = {};
    for (int r = 0; r < NNEI; ++r) {
      int bj = 0; double bv = 1e300; int bidx = 0x7fffffff;
      for (int j = 0; j < NCAND; ++j) {
        if (used[j]) continue;
        if (d2s[j] < bv || (d2s[j] == bv && cidxL[j] < bidx)) { bv = d2s[j]; bidx = cidxL[j]; bj = j; }
      }
      used[bj] = true;
      tki[(size_t)n * NNEI + r] = bidx;
      dacc += sqrt(bv > 0.0 ? bv : 0.0);
    }
    dsv[n] = (float)(dacc * (1.0 / 9.0));
  }
}

// ---------- global stats of row-mean distance (broadcast [N,C], ddof=1) ----------
__global__ __launch_bounds__(256) void stats_kernel(const float* __restrict__ dsv,
                                                    float* __restrict__ stats) {
  __shared__ float buf[NROWS];
  __shared__ float red[4];
  int tid = threadIdx.x;
  float s = 0.f;
  for (int i = tid; i < NROWS; i += 256) { float v = dsv[i]; buf[i] = v; s += v; }
#pragma unroll
  for (int off = 32; off; off >>= 1) s += __shfl_xor(s, off);
  if ((tid & 63) == 0) red[tid >> 6] = s;
  __syncthreads();
  float mu = (red[0] + red[1] + red[2] + red[3]) * (1.f / NROWS);
  __syncthreads();
  float q = 0.f;
  for (int i = tid; i < NROWS; i += 256) { float d = buf[i] - mu; q += d * d; }
#pragma unroll
  for (int off = 32; off; off >>= 1) q += __shfl_xor(q, off);
  if ((tid & 63) == 0) red[tid >> 6] = q;
  __syncthreads();
  if (tid == 0) {
    float SSb = (red[0] + red[1] + red[2] + red[3]) * (float)NC;
    float var = SSb / ((float)NROWS * (float)NC - 1.f);
    stats[0] = mu;
    stats[1] = 1.f / (sqrtf(var) + 1e-8f);
  }
}

// ---------- fused: gather 9 neighbors (bf16 bank), influence norm, noise, maps ----------
__global__ __launch_bounds__(256) void fuse_kernel(const float* __restrict__ Af32,
                                                   const __bf16* __restrict__ Bhi,
                                                   const float* __restrict__ noise,
                                                   const float* __restrict__ iw,
                                                   const float* __restrict__ dwp,
                                                   const int* __restrict__ topk_idx,
                                                   const float* __restrict__ dsv,
                                                   const float* __restrict__ stats,
                                                   float* __restrict__ noised_tmp,
                                                   float* __restrict__ out_infl,
                                                   float* __restrict__ out_nstd) {
  __shared__ int idx[NNEI];
  __shared__ float red[4];
  int n = blockIdx.x;
  int tid = threadIdx.x;
  if (tid < NNEI) idx[tid] = topk_idx[(size_t)n * NNEI + tid];
  __syncthreads();

  int c0 = tid * 8;
  const float* frow = Af32 + (size_t)n * NC + c0;
  float4 fa = *(const float4*)frow;
  float4 fb = *(const float4*)(frow + 4);
  float f_c[8] = {fa.x, fa.y, fa.z, fa.w, fb.x, fb.y, fb.z, fb.w};
  float a_c[8] = {};
  for (int j = 0; j < NNEI; ++j) {
    bf16x8 mv = *(const bf16x8*)(Bhi + (size_t)idx[j] * NC + c0);
#pragma unroll
    for (int k = 0; k < 8; ++k) a_c[k] += fabsf(f_c[k] - (float)mv[k]);
  }
  float4 w0 = *(const float4*)(iw + c0);
  float4 w1 = *(const float4*)(iw + c0 + 4);
  float wv[8] = {w0.x, w0.y, w0.z, w0.w, w1.x, w1.y, w1.z, w1.w};
  float s_c[8];
  float sum_s = 0.f, sum_s2 = 0.f;
#pragma unroll
  for (int k = 0; k < 8; ++k) {
    float s = (a_c[k] * (1.f / 9.f)) * wv[k];
    s_c[k] = s;
    sum_s += s;
    sum_s2 += s * s;
  }
#pragma unroll
  for (int off = 32; off; off >>= 1) sum_s += __shfl_xor(sum_s, off);
  if ((tid & 63) == 0) red[tid >> 6] = sum_s;
  __syncthreads();
  float tot_s = red[0] + red[1] + red[2] + red[3];
  __syncthreads();
#pragma unroll
  for (int off = 32; off; off >>= 1) sum_s2 += __shfl_xor(sum_s2, off);
  if ((tid & 63) == 0) red[tid >> 6] = sum_s2;
  __syncthreads();
  float tot_s2 = red[0] + red[1] + red[2] + red[3];
  __syncthreads();

  float mu = tot_s * (1.f / NC);
  float var = (tot_s2 - (float)NC * mu * mu) * (1.f / (NC - 1));
  float rstd = 1.f / (sqrtf(fmaxf(var, 0.f)) + 1e-8f);
  float dnorm = (dsv[n] - stats[0]) * stats[1];
  float dwv = dwp[0];

  float4 na = *(const float4*)(noise + (size_t)n * NC + c0);
  float4 nb = *(const float4*)(noise + (size_t)n * NC + c0 + 4);
  float nz[8] = {na.x, na.y, na.z, na.w, nb.x, nb.y, nb.z, nb.w};
  float o[8];
  float nsum = 0.f;
#pragma unroll
  for (int k = 0; k < 8; ++k) {
    float inorm = (s_c[k] - mu) * rstd;
    float comb = inorm + dwv * dnorm;
    float sig = 1.f / (1.f + expf(-comb));
    float nstd = 0.01f + 0.49f * sig;
    nsum += nstd;
    o[k] = f_c[k] + nz[k] * nstd;
  }
  float* orow = noised_tmp + (size_t)n * NC + c0;
  *(float4*)orow = make_float4(o[0], o[1], o[2], o[3]);
  *(float4*)(orow + 4) = make_float4(o[4], o[5], o[6], o[7]);
#pragma unroll
  for (int off = 32; off; off >>= 1) nsum += __shfl_xor(nsum, off);
  if ((tid & 63) == 0) red[tid >> 6] = nsum;
  __syncthreads();
  if (tid == 0) {
    out_infl[n] = tot_s * (1.f / NC);
    out_nstd[n] = (red[0] + red[1] + red[2] + red[3]) * (1.f / NC);
  }
}

// ---------- transpose noised [N,C] -> [B,C,H,W] ----------
__global__ __launch_bounds__(256) void transpose_kernel(const float* __restrict__ src,
                                                        float* __restrict__ dst) {
  __shared__ float tile[32][33];
  int b = blockIdx.z;
  int c0 = blockIdx.y * 32;
  int hw0 = blockIdx.x * 32;
  int tx = threadIdx.x & 31, ty = threadIdx.x >> 5;
#pragma unroll
  for (int i = 0; i < 4; ++i) {
    int hw = hw0 + ty + i * 8;
    if (hw < NHW) tile[ty + i * 8][tx] = src[((size_t)(b * NHW + hw)) * NC + c0 + tx];
  }
  __syncthreads();
#pragma unroll
  for (int i = 0; i < 4; ++i) {
    int c = c0 + ty + i * 8;
    int hw = hw0 + tx;
    if (hw < NHW) dst[((size_t)b * NC + c) * NHW + hw] = tile[tx][ty + i * 8];
  }
}

extern "C" void kernel_launch(void* const* d_in, const int* in_sizes, int n_in,
                              void* d_out, int out_size, void* d_ws, size_t ws_size,
                              hipStream_t stream) {
  (void)in_sizes; (void)n_in; (void)out_size; (void)ws_size;
  const float* feat  = (const float*)d_in[0];
  const float* mb    = (const float*)d_in[1];
  const float* iw    = (const float*)d_in[2];
  const float* dwp   = (const float*)d_in[3];
  const float* noise = (const float*)d_in[4];
  float* out = (float*)d_out;
  float* out_noised = out;
  float* out_infl = out + (size_t)NB * NC * NHW;
  float* out_nstd = out_infl + NROWS;

  char* ws = (char*)d_ws;
  size_t off = 0;
  auto alloc = [&](size_t sz) -> char* {
    char* p = ws + off;
    off += (sz + 255) & ~(size_t)255;
    return p;
  };
  float* Af32 = (float*)alloc((size_t)NROWS * NC * 4);
  signed char* Ai8 = (signed char*)alloc((size_t)NROWS * NC);
  signed char* Bi8 = (signed char*)alloc((size_t)NM * NC);
  __bf16* Bhi = (__bf16*)alloc((size_t)NM * NC * 2);   // stays live through fuse
  float* m2v = (float*)alloc((size_t)NM * 4);
  int* tki = (int*)alloc((size_t)NROWS * NNEI * 4);
  float* dsv = (float*)alloc((size_t)NROWS * 4);
  float* stv = (float*)alloc(256);
  unsigned short* dotq = (unsigned short*)alloc((size_t)NROWS * NM * 2);
  // noised_tmp overlays dotq (dead after selres); 51.4MB <= 102.8MB
  float* noised_tmp = (float*)dotq;

  prep_kernel<<<12800 + NM, 256, 0, stream>>>(feat, mb, Af32, Ai8, Bi8, Bhi, m2v);
  gemm8_kernel<<<1024, 512, 0, stream>>>(Ai8, Bi8, m2v, dotq);
  selres_kernel<<<NROWS, 512, 0, stream>>>(dotq, Af32, mb, tki, dsv);
  stats_kernel<<<1, 256, 0, stream>>>(dsv, stv);
  fuse_kernel<<<NROWS, 256, 0, stream>>>(Af32, Bhi, noise, iw, dwp, tki, dsv, stv,
                                         noised_tmp, out_infl, out_nstd);
  transpose_kernel<<<dim3(25, 64, NB), 256, 0, stream>>>(noised_tmp, out_noised);
}

// Round 20
// 440.300 us; speedup vs baseline: 1.4467x; 1.4467x over previous
//
#include <hip/hip_runtime.h>
#include <math.h>

typedef __attribute__((ext_vector_type(8))) __bf16 bf16x8;
typedef __attribute__((ext_vector_type(4))) float f32x4;

#define NB 8
#define NC 2048
#define NHW 784
#define NROWS 6272   /* NB*NHW */
#define NM 8192
#define NNEI 9
#define NCAND 12
#define NKT 64       /* K-tiles of 32 */

static_assert(NROWS == NB * NHW, "dims");

__device__ __forceinline__ unsigned umin32(unsigned a, unsigned b) { return a < b ? a : b; }

// ---------- merged prep: feat transpose->Af32/Ahi (bid<12800) | mb->Bhi+m2 ----------
__global__ __launch_bounds__(256) void prep_kernel(const float* __restrict__ feat,
                                                   const float* __restrict__ mb,
                                                   float* __restrict__ Af32,
                                                   __bf16* __restrict__ Ahi,
                                                   __bf16* __restrict__ Bhi,
                                                   float* __restrict__ m2) {
  int bid = blockIdx.x;
  int tid = threadIdx.x;
  if (bid < 12800) {
    __shared__ float tile[32][33];
    int b = bid / 1600;
    int c0 = ((bid / 25) & 63) * 32;
    int hw0 = (bid % 25) * 32;
    int tx = tid & 31, ty = tid >> 5;
#pragma unroll
    for (int i = 0; i < 4; ++i) {
      int c = c0 + ty + i * 8;
      int hw = hw0 + tx;
      float v = 0.f;
      if (hw < NHW) v = feat[((size_t)b * NC + c) * NHW + hw];
      tile[ty + i * 8][tx] = v;
    }
    __syncthreads();
#pragma unroll
    for (int i = 0; i < 4; ++i) {
      int hwl = ty + i * 8;
      int hw = hw0 + hwl;
      if (hw < NHW) {
        int n = b * NHW + hw;
        float v = tile[tx][hwl];
        Af32[(size_t)n * NC + c0 + tx] = v;
        Ahi[(size_t)n * NC + c0 + tx] = (__bf16)v;
      }
    }
  } else {
    __shared__ float red[4];
    int m = bid - 12800;
    float ss = 0.f;
#pragma unroll
    for (int i = 0; i < NC / 256; ++i) {
      int c = tid + i * 256;
      float v = mb[(size_t)m * NC + c];
      Bhi[(size_t)m * NC + c] = (__bf16)v;
      ss += v * v;
    }
#pragma unroll
    for (int off = 32; off; off >>= 1) ss += __shfl_xor(ss, off);
    if ((tid & 63) == 0) red[tid >> 6] = ss;
    __syncthreads();
    if (tid == 0) m2[m] = red[0] + red[1] + red[2] + red[3];
  }
}

#define STAGE(SRC, DST) \
  __builtin_amdgcn_global_load_lds((const __attribute__((address_space(1))) void*)(SRC), \
                                   (__attribute__((address_space(3))) void*)(DST), 16, 0, 0)

// ---------- mixed-shape GEMM dispatch (tail-packed) — R11 config, unchanged ----------
__global__ __launch_bounds__(512, 2) void gemm8_kernel(const __bf16* __restrict__ Ahi,
                                                       const __bf16* __restrict__ Bhi,
                                                       const float* __restrict__ m2,
                                                       unsigned short* __restrict__ dotq) {
  __shared__ __align__(16) char lds[131072];
  int tid = threadIdx.x;
  int lane = tid & 63, w = tid >> 6;
  int bid = blockIdx.x;
  int r = lane & 15, kq = lane >> 4;
  int r4 = (lane >> 4) * 4, cL = lane & 15;  // C/D: col=lane&15, row=(lane>>4)*4+reg (m89)

  if (bid >= 768) {
    // ---------- light path: rows 6144..6271, 32 cols/block, prefetched ----------
    int lb = bid - 768;
    size_t m0l = (size_t)(lb & 7) * 1024 + (size_t)(lb >> 3) * 32;  // XCD-stripe aligned
    int n0l = 6144 + w * 16;
    const __bf16* aB = Ahi + (size_t)(n0l + r) * NC + kq * 8;
    const __bf16* bB0 = Bhi + (m0l + r) * NC + kq * 8;
    const __bf16* bB1 = Bhi + (m0l + 16 + r) * NC + kq * 8;
    f32x4 acc0 = {}, acc1 = {};
    bf16x8 a0 = *(const bf16x8*)aB;
    bf16x8 b0 = *(const bf16x8*)bB0;
    bf16x8 b1 = *(const bf16x8*)bB1;
#pragma unroll 4
    for (int kt = 0; kt < NKT; ++kt) {
      int ktn = (kt + 1) & 63;                 // wrap prefetch at tail: harmless
      bf16x8 an = *(const bf16x8*)(aB + ktn * 32);
      bf16x8 b0n = *(const bf16x8*)(bB0 + ktn * 32);
      bf16x8 b1n = *(const bf16x8*)(bB1 + ktn * 32);
      acc0 = __builtin_amdgcn_mfma_f32_16x16x32_bf16(a0, b0, acc0, 0, 0, 0);
      acc1 = __builtin_amdgcn_mfma_f32_16x16x32_bf16(a0, b1, acc1, 0, 0, 0);
      a0 = an; b0 = b0n; b1 = b1n;
    }
#pragma unroll
    for (int g = 0; g < 2; ++g) {
      float m2g = m2[m0l + g * 16 + cL];
      f32x4 ac = g ? acc1 : acc0;
#pragma unroll
      for (int q = 0; q < 4; ++q) {
        int grow = n0l + r4 + q;
        float sc = m2g - 2.f * ac[q];
        int qi = (int)(sc * 16.f);
        qi = qi < 0 ? 0 : (qi > 65535 ? 65535 : qi);
        dotq[(size_t)grow * NM + (m0l + g * 16 + cL)] = (unsigned short)qi;
      }
    }
    return;
  }

  // ---------- heavy path: 256x256 tile (rows 0..6143) ----------
  int xcd = bid & 7, lin = bid >> 3;
  int mt = xcd * 4 + (lin & 3), rtl = lin >> 2;        // rtl in [0,24)
  size_t n0 = (size_t)rtl * 256, m0 = (size_t)mt * 256;
  int wr = w >> 2, wc = w & 3;

  int p = lane & 3;
  const char* aSrc[2];
  const char* bSrc[2];
  int aDst[2], bDst[2];
#pragma unroll
  for (int j = 0; j < 2; ++j) {
    int rloc = (w * 2 + j) * 16 + (lane >> 2);
    int kqs = (p - (rloc >> 1)) & 3;            // inverse of read swizzle
    aSrc[j] = (const char*)Ahi + (n0 + rloc) * (NC * 2) + kqs * 16;
    bSrc[j] = (const char*)Bhi + (m0 + rloc) * (NC * 2) + kqs * 16;
    aDst[j] = (w * 2 + j) * 1024;
    bDst[j] = 16384 + (w * 2 + j) * 1024;
  }
  int s16 = (kq + (r >> 1)) & 3;                // 2-way bank aliasing only (free)
  int aRd = wr * 8192 + r * 64 + s16 * 16;
  int bRd = 16384 + wc * 4096 + r * 64 + s16 * 16;

  f32x4 acc[8][4] = {};

#pragma unroll
  for (int t = 0; t < 2; ++t) {
    int sb = t * 32768, kb = t * 64;
#pragma unroll
    for (int j = 0; j < 2; ++j)
      STAGE(aSrc[j] + kb, lds + sb + aDst[j]);
#pragma unroll
    for (int j = 0; j < 2; ++j)
      STAGE(bSrc[j] + kb, lds + sb + bDst[j]);
  }
  asm volatile("s_waitcnt vmcnt(4)" ::: "memory");   // K0 landed
  __builtin_amdgcn_s_barrier();
  __builtin_amdgcn_sched_barrier(0);

#pragma unroll 4
  for (int kt = 0; kt < NKT; ++kt) {
    int sb = (kt & 3) * 32768;
    int kt2 = (kt + 2) & 63;                    // wraps at tail: harmless re-stage
    int sb2 = (kt2 & 3) * 32768;
    int kb2 = kt2 * 64;
    bf16x8 av[4], bv[4];
    // ---- P1: stage A(T+2) | read A0-3 + B0-3 | 16 MFMA (no barrier) ----
#pragma unroll
    for (int j = 0; j < 2; ++j)
      STAGE(aSrc[j] + kb2, lds + sb2 + aDst[j]);
#pragma unroll
    for (int f = 0; f < 4; ++f) av[f] = *(const bf16x8*)(lds + sb + aRd + f * 1024);
#pragma unroll
    for (int g = 0; g < 4; ++g) bv[g] = *(const bf16x8*)(lds + sb + bRd + g * 1024);
    __builtin_amdgcn_s_setprio(1);
#pragma unroll
    for (int f = 0; f < 4; ++f)
#pragma unroll
      for (int g = 0; g < 4; ++g)
        acc[f][g] = __builtin_amdgcn_mfma_f32_16x16x32_bf16(av[f], bv[g], acc[f][g], 0, 0, 0);
    __builtin_amdgcn_s_setprio(0);
    // ---- P2: stage B(T+2) | read A4-7 | 16 MFMA (no barrier) ----
#pragma unroll
    for (int j = 0; j < 2; ++j)
      STAGE(bSrc[j] + kb2, lds + sb2 + bDst[j]);
#pragma unroll
    for (int f = 0; f < 4; ++f) av[f] = *(const bf16x8*)(lds + sb + aRd + (f + 4) * 1024);
    __builtin_amdgcn_s_setprio(1);
#pragma unroll
    for (int f = 0; f < 4; ++f)
#pragma unroll
      for (int g = 0; g < 4; ++g)
        acc[f + 4][g] = __builtin_amdgcn_mfma_f32_16x16x32_bf16(av[f], bv[g], acc[f + 4][g], 0, 0, 0);
    __builtin_amdgcn_s_setprio(0);
    // ---- boundary: counted wait (never 0): T+1 certified landed ----
    asm volatile("s_waitcnt vmcnt(4)" ::: "memory");
    __builtin_amdgcn_s_barrier();
    __builtin_amdgcn_sched_barrier(0);
  }

  float m2r[4];
#pragma unroll
  for (int g = 0; g < 4; ++g) m2r[g] = m2[m0 + wc * 64 + g * 16 + cL];
#pragma unroll
  for (int f = 0; f < 8; ++f) {
    int grow0 = (int)n0 + wr * 128 + f * 16 + r4;
#pragma unroll
    for (int g = 0; g < 4; ++g) {
      size_t gcol = m0 + wc * 64 + g * 16 + cL;
#pragma unroll
      for (int q = 0; q < 4; ++q) {
        float sc = m2r[g] - 2.f * acc[f][g][q];
        int qi = (int)(sc * 16.f);
        qi = qi < 0 ? 0 : (qi > 65535 ? 65535 : qi);
        dotq[(size_t)(grow0 + q) * NM + gcol] = (unsigned short)qi;
      }
    }
  }
}

// ---------- fused: register-tournament top-12 + wave-parallel fp64 rescore ----------
__global__ __launch_bounds__(256) void selres_kernel(const unsigned short* __restrict__ dotq,
                                                     const float* __restrict__ Af32,
                                                     const float* __restrict__ mb,
                                                     int* __restrict__ tki,
                                                     float* __restrict__ dsv) {
  __shared__ float fbuf[NC];
  __shared__ unsigned wmin[4];
  __shared__ int cidxL[NCAND];
  __shared__ double d2s[NCAND];
  int n = blockIdx.x;
  int tid = threadIdx.x;
  int lane = tid & 63, w = tid >> 6;

  // 32 packed keys (q<<13 | m) in registers; all accesses static after unroll
  unsigned kk[32];
  {
    const uint4* dq = (const uint4*)(dotq + (size_t)n * NM + tid * 32);
    unsigned base = tid * 32;
#pragma unroll
    for (int s = 0; s < 4; ++s) {
      uint4 v = dq[s];
      unsigned c0 = v.x, c1 = v.y, c2 = v.z, c3 = v.w;
      kk[s * 8 + 0] = ((c0 & 0xFFFFu) << 13) | (base + s * 8 + 0);
      kk[s * 8 + 1] = ((c0 >> 16) << 13)     | (base + s * 8 + 1);
      kk[s * 8 + 2] = ((c1 & 0xFFFFu) << 13) | (base + s * 8 + 2);
      kk[s * 8 + 3] = ((c1 >> 16) << 13)     | (base + s * 8 + 3);
      kk[s * 8 + 4] = ((c2 & 0xFFFFu) << 13) | (base + s * 8 + 4);
      kk[s * 8 + 5] = ((c2 >> 16) << 13)     | (base + s * 8 + 5);
      kk[s * 8 + 6] = ((c3 & 0xFFFFu) << 13) | (base + s * 8 + 6);
      kk[s * 8 + 7] = ((c3 >> 16) << 13)     | (base + s * 8 + 7);
    }
  }
#pragma unroll
  for (int i = 0; i < NC / 256; ++i)
    fbuf[tid + i * 256] = Af32[(size_t)n * NC + tid + i * 256];

  unsigned lmin = 0xFFFFFFFFu;
#pragma unroll
  for (int i = 0; i < 32; ++i) lmin = umin32(lmin, kk[i]);
  unsigned t = lmin;
#pragma unroll
  for (int off = 32; off; off >>= 1) t = umin32(t, (unsigned)__shfl_xor((int)t, off));
  if (lane == 0) wmin[w] = t;
  __syncthreads();

  for (int r = 0; r < NCAND; ++r) {
    unsigned g = umin32(umin32(wmin[0], wmin[1]), umin32(wmin[2], wmin[3]));
    if (tid == 0) cidxL[r] = (int)(g & 8191u);
    __syncthreads();                       // all reads of wmin done before owner updates
    int owner = (int)((g & 8191u) >> 5);   // thread that holds key g
    if ((owner >> 6) == w) {
      if (tid == owner) {
#pragma unroll
        for (int i = 0; i < 32; ++i)
          if (kk[i] == g) kk[i] = 0xFFFFFFFFu;
        lmin = 0xFFFFFFFFu;
#pragma unroll
        for (int i = 0; i < 32; ++i) lmin = umin32(lmin, kk[i]);
      }
      unsigned t2 = lmin;
#pragma unroll
      for (int off = 32; off; off >>= 1) t2 = umin32(t2, (unsigned)__shfl_xor((int)t2, off));
      if (lane == 0) wmin[w] = t2;
    }
    __syncthreads();
  }

  // wave-parallel exact fp64 rescore: wave w -> candidates 3w..3w+2
#pragma unroll
  for (int jj = 0; jj < 3; ++jj) {
    int j = w * 3 + jj;
    const float* mrow = mb + (size_t)cidxL[j] * NC;
    double acc = 0.0;
#pragma unroll
    for (int i = 0; i < 32; ++i) {
      int c = lane + i * 64;
      double d = (double)fbuf[c] - (double)mrow[c];
      acc += d * d;
    }
#pragma unroll
    for (int off = 32; off; off >>= 1) acc += __shfl_xor(acc, off);
    if (lane == 0) d2s[j] = acc;
  }
  __syncthreads();

  if (tid == 0) {
    double dacc = 0.0;
    bool used[NCAND] = {};
    for (int r = 0; r < NNEI; ++r) {
      int bj = 0; double bv = 1e300; int bidx = 0x7fffffff;
      for (int j = 0; j < NCAND; ++j) {
        if (used[j]) continue;
        if (d2s[j] < bv || (d2s[j] == bv && cidxL[j] < bidx)) { bv = d2s[j]; bidx = cidxL[j]; bj = j; }
      }
      used[bj] = true;
      tki[(size_t)n * NNEI + r] = bidx;
      dacc += sqrt(bv > 0.0 ? bv : 0.0);
    }
    dsv[n] = (float)(dacc * (1.0 / 9.0));
  }
}

// ---------- global stats of row-mean distance (broadcast [N,C], ddof=1) ----------
__global__ __launch_bounds__(256) void stats_kernel(const float* __restrict__ dsv,
                                                    float* __restrict__ stats) {
  __shared__ float buf[NROWS];
  __shared__ float red[4];
  int tid = threadIdx.x;
  float s = 0.f;
  for (int i = tid; i < NROWS; i += 256) { float v = dsv[i]; buf[i] = v; s += v; }
#pragma unroll
  for (int off = 32; off; off >>= 1) s += __shfl_xor(s, off);
  if ((tid & 63) == 0) red[tid >> 6] = s;
  __syncthreads();
  float mu = (red[0] + red[1] + red[2] + red[3]) * (1.f / NROWS);
  __syncthreads();
  float q = 0.f;
  for (int i = tid; i < NROWS; i += 256) { float d = buf[i] - mu; q += d * d; }
#pragma unroll
  for (int off = 32; off; off >>= 1) q += __shfl_xor(q, off);
  if ((tid & 63) == 0) red[tid >> 6] = q;
  __syncthreads();
  if (tid == 0) {
    float SSb = (red[0] + red[1] + red[2] + red[3]) * (float)NC;
    float var = SSb / ((float)NROWS * (float)NC - 1.f);
    stats[0] = mu;
    stats[1] = 1.f / (sqrtf(var) + 1e-8f);
  }
}

// ---------- fused: gather 9 neighbors (bf16 bank), influence norm, noise, maps ----------
__global__ __launch_bounds__(256) void fuse_kernel(const float* __restrict__ Af32,
                                                   const __bf16* __restrict__ Bhi,
                                                   const float* __restrict__ noise,
                                                   const float* __restrict__ iw,
                                                   const float* __restrict__ dwp,
                                                   const int* __restrict__ topk_idx,
                                                   const float* __restrict__ dsv,
                                                   const float* __restrict__ stats,
                                                   float* __restrict__ noised_tmp,
                                                   float* __restrict__ out_infl,
                                                   float* __restrict__ out_nstd) {
  __shared__ int idx[NNEI];
  __shared__ float red[4];
  int n = blockIdx.x;
  int tid = threadIdx.x;
  if (tid < NNEI) idx[tid] = topk_idx[(size_t)n * NNEI + tid];
  __syncthreads();

  int c0 = tid * 8;
  const float* frow = Af32 + (size_t)n * NC + c0;
  float4 fa = *(const float4*)frow;
  float4 fb = *(const float4*)(frow + 4);
  float f_c[8] = {fa.x, fa.y, fa.z, fa.w, fb.x, fb.y, fb.z, fb.w};
  float a_c[8] = {};
  for (int j = 0; j < NNEI; ++j) {
    bf16x8 mv = *(const bf16x8*)(Bhi + (size_t)idx[j] * NC + c0);
#pragma unroll
    for (int k = 0; k < 8; ++k) a_c[k] += fabsf(f_c[k] - (float)mv[k]);
  }
  float4 w0 = *(const float4*)(iw + c0);
  float4 w1 = *(const float4*)(iw + c0 + 4);
  float wv[8] = {w0.x, w0.y, w0.z, w0.w, w1.x, w1.y, w1.z, w1.w};
  float s_c[8];
  float sum_s = 0.f, sum_s2 = 0.f;
#pragma unroll
  for (int k = 0; k < 8; ++k) {
    float s = (a_c[k] * (1.f / 9.f)) * wv[k];
    s_c[k] = s;
    sum_s += s;
    sum_s2 += s * s;
  }
#pragma unroll
  for (int off = 32; off; off >>= 1) sum_s += __shfl_xor(sum_s, off);
  if ((tid & 63) == 0) red[tid >> 6] = sum_s;
  __syncthreads();
  float tot_s = red[0] + red[1] + red[2] + red[3];
  __syncthreads();
#pragma unroll
  for (int off = 32; off; off >>= 1) sum_s2 += __shfl_xor(sum_s2, off);
  if ((tid & 63) == 0) red[tid >> 6] = sum_s2;
  __syncthreads();
  float tot_s2 = red[0] + red[1] + red[2] + red[3];
  __syncthreads();

  float mu = tot_s * (1.f / NC);
  float var = (tot_s2 - (float)NC * mu * mu) * (1.f / (NC - 1));
  float rstd = 1.f / (sqrtf(fmaxf(var, 0.f)) + 1e-8f);
  float dnorm = (dsv[n] - stats[0]) * stats[1];
  float dwv = dwp[0];

  float4 na = *(const float4*)(noise + (size_t)n * NC + c0);
  float4 nb = *(const float4*)(noise + (size_t)n * NC + c0 + 4);
  float nz[8] = {na.x, na.y, na.z, na.w, nb.x, nb.y, nb.z, nb.w};
  float o[8];
  float nsum = 0.f;
#pragma unroll
  for (int k = 0; k < 8; ++k) {
    float inorm = (s_c[k] - mu) * rstd;
    float comb = inorm + dwv * dnorm;
    float sig = 1.f / (1.f + expf(-comb));
    float nstd = 0.01f + 0.49f * sig;
    nsum += nstd;
    o[k] = f_c[k] + nz[k] * nstd;
  }
  float* orow = noised_tmp + (size_t)n * NC + c0;
  *(float4*)orow = make_float4(o[0], o[1], o[2], o[3]);
  *(float4*)(orow + 4) = make_float4(o[4], o[5], o[6], o[7]);
#pragma unroll
  for (int off = 32; off; off >>= 1) nsum += __shfl_xor(nsum, off);
  if ((tid & 63) == 0) red[tid >> 6] = nsum;
  __syncthreads();
  if (tid == 0) {
    out_infl[n] = tot_s * (1.f / NC);
    out_nstd[n] = (red[0] + red[1] + red[2] + red[3]) * (1.f / NC);
  }
}

// ---------- transpose noised [N,C] -> [B,C,H,W] ----------
__global__ __launch_bounds__(256) void transpose_kernel(const float* __restrict__ src,
                                                        float* __restrict__ dst) {
  __shared__ float tile[32][33];
  int b = blockIdx.z;
  int c0 = blockIdx.y * 32;
  int hw0 = blockIdx.x * 32;
  int tx = threadIdx.x & 31, ty = threadIdx.x >> 5;
#pragma unroll
  for (int i = 0; i < 4; ++i) {
    int hw = hw0 + ty + i * 8;
    if (hw < NHW) tile[ty + i * 8][tx] = src[((size_t)(b * NHW + hw)) * NC + c0 + tx];
  }
  __syncthreads();
#pragma unroll
  for (int i = 0; i < 4; ++i) {
    int c = c0 + ty + i * 8;
    int hw = hw0 + tx;
    if (hw < NHW) dst[((size_t)b * NC + c) * NHW + hw] = tile[tx][ty + i * 8];
  }
}

extern "C" void kernel_launch(void* const* d_in, const int* in_sizes, int n_in,
                              void* d_out, int out_size, void* d_ws, size_t ws_size,
                              hipStream_t stream) {
  (void)in_sizes; (void)n_in; (void)out_size; (void)ws_size;
  const float* feat  = (const float*)d_in[0];
  const float* mb    = (const float*)d_in[1];
  const float* iw    = (const float*)d_in[2];
  const float* dwp   = (const float*)d_in[3];
  const float* noise = (const float*)d_in[4];
  float* out = (float*)d_out;
  float* out_noised = out;
  float* out_infl = out + (size_t)NB * NC * NHW;
  float* out_nstd = out_infl + NROWS;

  char* ws = (char*)d_ws;
  size_t off = 0;
  auto alloc = [&](size_t sz) -> char* {
    char* p = ws + off;
    off += (sz + 255) & ~(size_t)255;
    return p;
  };
  float* Af32 = (float*)alloc((size_t)NROWS * NC * 4);
  __bf16* Ahi = (__bf16*)alloc((size_t)NROWS * NC * 2);
  __bf16* Bhi = (__bf16*)alloc((size_t)NM * NC * 2);   // stays live through fuse
  float* m2v = (float*)alloc((size_t)NM * 4);
  int* tki = (int*)alloc((size_t)NROWS * NNEI * 4);
  float* dsv = (float*)alloc((size_t)NROWS * 4);
  float* stv = (float*)alloc(256);
  unsigned short* dotq = (unsigned short*)alloc((size_t)NROWS * NM * 2);
  // noised_tmp overlays dotq (dead after selres); 51.4MB <= 102.8MB
  float* noised_tmp = (float*)dotq;

  prep_kernel<<<12800 + NM, 256, 0, stream>>>(feat, mb, Af32, Ahi, Bhi, m2v);
  gemm8_kernel<<<1024, 512, 0, stream>>>(Ahi, Bhi, m2v, dotq);
  selres_kernel<<<NROWS, 256, 0, stream>>>(dotq, Af32, mb, tki, dsv);
  stats_kernel<<<1, 256, 0, stream>>>(dsv, stv);
  fuse_kernel<<<NROWS, 256, 0, stream>>>(Af32, Bhi, noise, iw, dwp, tki, dsv, stv,
                                         noised_tmp, out_infl, out_nstd);
  transpose_kernel<<<dim3(25, 64, NB), 256, 0, stream>>>(noised_tmp, out_noised);
}